// Round 1
// baseline (60.246 us; speedup 1.0000x reference)
//
#include <hip/hip_runtime.h>
#include <math.h>
#include <float.h>

#define NS 8
#define NA 64
#define NP 32
#define NT 80
#define NK 6

__global__ __launch_bounds__(256) void waymo_pp_kernel(
    const void* __restrict__ valid_raw,
    const float* __restrict__ scores,
    const float* __restrict__ trajs,
    const float* __restrict__ atype,
    float* __restrict__ out)
{
    const int blk = blockIdx.x;          // s*NA + a
    const int s = blk / NA;
    const int a = blk % NA;
    const int tid = threadIdx.x;

    __shared__ float2 sxy[NT][NP + 1];   // [t][p], +1 pad -> only 2-way (free) conflicts
    __shared__ unsigned wrow[NP];        // MTR within bitmask rows
    __shared__ float ssc[NP];            // scores (normalized in place)
    __shared__ int   sel[NK];
    __shared__ float s6[NK];
    __shared__ unsigned w6[NK];          // MPA within bitmask rows
    __shared__ float fsc[NK];
    __shared__ int vflag;

    // per-agent thresholds (agent_type is one-hot f32)
    const float at0 = atype[blk*3+0], at1 = atype[blk*3+1], at2 = atype[blk*3+2];
    const float thrM = at0*3.5f + at1*1.0f + at2*1.75f;
    const float thrQ = at0*2.5f + at1*1.0f + at2*1.5f;

    // ---- phase 0: init + stage ----
    if (tid < NP) { wrow[tid] = 1u << tid; ssc[tid] = scores[blk*NP + tid]; }
    if (tid < NK) w6[tid] = 1u << tid;
    if (tid == 0) {
        // detect valid[] encoding from first 512 bytes (safe for u8/i32/f32 layouts)
        const unsigned* w = (const unsigned*)valid_raw;
        int isF = 0, multi = 0;
        for (int i = 0; i < 128; ++i) {
            unsigned x = w[i];
            if (x == 0x3F800000u) isF = 1;
            int nz = ((x&0xFFu)!=0)+((x&0xFF00u)!=0)+((x&0xFF0000u)!=0)+((x&0xFF000000u)!=0);
            if (nz >= 2) multi = 1;
        }
        int v;
        if (isF)        v = (((const float*)valid_raw)[blk] != 0.0f);
        else if (multi) v = (((const unsigned char*)valid_raw)[blk] != 0);
        else            v = (((const int*)valid_raw)[blk] != 0);
        vflag = v;
    }
    const float4* tg = (const float4*)trajs + (size_t)blk * NP * NT;
    for (int l = tid; l < NP*NT; l += 256) {
        int p = l / NT, t = l - p*NT;
        float4 v = tg[l];                       // coalesced: consecutive (p,t)
        sxy[t][p] = make_float2(v.x, v.y);
    }
    __syncthreads();

    // ---- phase 1: MTR 32x32 within (upper triangle) ----
    for (int l = tid; l < NP*NP; l += 256) {
        int i = l / NP, j = l - i*NP;
        if (i >= j) continue;
        float acc = 0.0f;
        for (int t = 0; t < NT; ++t) {
            float2 pi = sxy[t][i], pj = sxy[t][j];
            float dx = pi.x - pj.x, dy = pi.y - pj.y;
            acc += sqrtf(dx*dx + dy*dy);
        }
        float ade = acc / (float)NT;
        if (ade < thrM) {
            atomicOr(&wrow[i], 1u << j);
            atomicOr(&wrow[j], 1u << i);
        }
    }
    __syncthreads();

    // ---- phase 2a: normalize scores over P ----
    if (tid < 64) {
        float v = (tid < NP) ? ssc[tid] : 0.0f;
        for (int off = 32; off; off >>= 1) v += __shfl_xor(v, off);
        if (tid < NP) ssc[tid] = ssc[tid] / v;
    }
    __syncthreads();

    // ---- phase 2b: greedy MTR NMS scan (wave 0; lane p holds carry[p]) ----
    if (tid < 64) {
        int lane = tid;
        float carry = (lane < NP) ? ssc[lane] : -FLT_MAX;
        for (int k = 0; k < NK; ++k) {
            // argmax with first-index tie-break (matches jnp.argmax)
            float v = carry; int bi = lane;
            for (int off = 32; off; off >>= 1) {
                float ov = __shfl_xor(v, off);
                int   oi = __shfl_xor(bi, off);
                if (ov > v || (ov == v && oi < bi)) { v = ov; bi = oi; }
            }
            unsigned row = wrow[bi];
            if (lane == bi) carry = -1.0f;
            else if (lane < NP) carry *= ((row >> lane) & 1u) ? 0.01f : 1.0f;
            if (lane == 0) sel[k] = bi;
        }
    }
    __syncthreads();

    if (tid < NK) s6[tid] = ssc[sel[tid]];   // gather normalized scores of winners
    __syncthreads();

    // ---- phase 3: MPA 6x6 within on selected trajectories ----
    if (tid < 15) {
        int ii = 0, jj = 1, c = 0;
        for (int i = 0; i < NK; ++i)
            for (int j = i+1; j < NK; ++j) { if (c == tid) { ii = i; jj = j; } ++c; }
        int pi = sel[ii], pj = sel[jj];
        float acc = 0.0f;
        for (int t = 0; t < NT; ++t) {
            float2 qi = sxy[t][pi], qj = sxy[t][pj];
            float dx = qi.x - qj.x, dy = qi.y - qj.y;
            acc += sqrtf(dx*dx + dy*dy);
        }
        if (acc / (float)NT < thrQ) {
            atomicOr(&w6[ii], 1u << jj);
            atomicOr(&w6[jj], 1u << ii);
        }
    }
    __syncthreads();

    // ---- phase 4: serial MPA scan + temp softmax (thread 0, tiny) ----
    if (tid == 0) {
        float c[NK]; float sum = 0.0f;
        for (int i = 0; i < NK; ++i) { c[i] = s6[i]; sum += c[i]; }
        for (int i = 0; i < NK; ++i) c[i] /= sum;          // scores_k normalize
        // stable argsort(-s): ties -> smaller index first (matches jnp.argsort)
        float orig[NK]; int order[NK]; bool used[NK];
        for (int i = 0; i < NK; ++i) { orig[i] = c[i]; used[i] = false; }
        for (int m = 0; m < NK; ++m) {
            int best = -1;
            for (int i = 0; i < NK; ++i)
                if (!used[i] && (best < 0 || orig[i] > orig[best])) best = i;
            used[best] = true; order[m] = best;
        }
        int v = vflag;
        for (int m = 0; m < NK; ++m) {         // exact lax.scan carry semantics
            int k = order[m];
            bool sup = false;
            for (int j = 0; j < NK; ++j)
                if (((w6[k] >> j) & 1u) && c[j] > c[k]) sup = true;
            if (v && sup) c[k] = 0.001f;
        }
        sum = 0.0f;
        for (int i = 0; i < NK; ++i) sum += c[i];
        for (int i = 0; i < NK; ++i) c[i] /= sum;          // mpa normalize
        // softmax(log(c)/TEMP)
        float li[NK], mx = -FLT_MAX;
        for (int i = 0; i < NK; ++i) { li[i] = logf(c[i]) / 0.8f; mx = fmaxf(mx, li[i]); }
        float es = 0.0f;
        for (int i = 0; i < NK; ++i) { li[i] = expf(li[i] - mx); es += li[i]; }
        for (int i = 0; i < NK; ++i) fsc[i] = li[i] / es;
    }
    __syncthreads();

    // ---- phase 5: outputs ----
    const size_t base1 = (size_t)NS*NT*NA*NK*2;        // after waymo_trajs
    const size_t base2 = base1 + (size_t)NS*NT*NA*NK;  // after yaw
    const size_t base3 = base2 + (size_t)NS*NT*NA*NK;  // after spd
    const size_t base4 = base3 + (size_t)NS*NA*NK;     // after scores

    for (int l = tid; l < NK*NT; l += 256) {
        int k = l / NT, t = l - k*NT;
        float4 g = tg[sel[k]*NT + t];
        size_t o = (((size_t)(s*NT + t)*NA + a)*NK + k);
        out[o*2+0]     = g.x;
        out[o*2+1]     = g.y;
        out[base1 + o] = g.z;
        out[base2 + o] = g.w;
    }
    if (tid < NK) out[base3 + (size_t)blk*NK + tid] = fsc[tid];
    float vf = vflag ? 1.0f : 0.0f;
    for (int t = tid; t < NT; t += 256) out[base4 + (size_t)(s*NT + t)*NA + a] = vf;
}

extern "C" void kernel_launch(void* const* d_in, const int* in_sizes, int n_in,
                              void* d_out, int out_size, void* d_ws, size_t ws_size,
                              hipStream_t stream) {
    const void*  valid  = d_in[0];
    const float* scores = (const float*)d_in[1];
    const float* trajs  = (const float*)d_in[2];
    const float* atype  = (const float*)d_in[3];
    waymo_pp_kernel<<<NS*NA, 256, 0, stream>>>(valid, scores, trajs, atype, (float*)d_out);
}